// Round 2
// baseline (285.453 us; speedup 1.0000x reference)
//
#include <hip/hip_runtime.h>
#include <hip/hip_bf16.h>
#include <stdint.h>

// B=4, T=4096, K=256, D=1024, H=16, hd=64
#define D_DIM 1024

using f32x4  = __attribute__((ext_vector_type(4))) float;
using short8 = __attribute__((ext_vector_type(8))) short;

__device__ __forceinline__ float bf2f(unsigned short u) {
    union { unsigned int i; float f; } v; v.i = ((unsigned int)u) << 16; return v.f;
}
__device__ __forceinline__ unsigned short f2bf(float f) {
    union { float f; unsigned int i; } v; v.f = f;
    unsigned int x = v.i;
    return (unsigned short)((x + 0x7fffu + ((x >> 16) & 1u)) >> 16);  // RNE
}
__device__ __forceinline__ void gload16(const void* g, void* l) {
    __builtin_amdgcn_global_load_lds(
        (const __attribute__((address_space(1))) void*)g,
        (__attribute__((address_space(3))) void*)l, 16, 0, 0);
}

// ---------------------------------------------------------------------------
// Weight fold+split: W' = gamma ⊙ W  (per input-dim i), split f32 -> hi+lo bf16.
// sel 0..2 (Wq,Wk,Wv): hi at ws+sel*4MB, lo at +2MB.  sel 3 (Wo): plain bf16 @12MB.
// ---------------------------------------------------------------------------
__global__ __launch_bounds__(256)
void convw_kernel(const float* __restrict__ Wq, const float* __restrict__ Wk,
                  const float* __restrict__ Wv, const float* __restrict__ Wo,
                  const float* __restrict__ gq, const float* __restrict__ gkv,
                  char* __restrict__ ws)
{
    const int e   = (blockIdx.x * 256 + threadIdx.x) * 4;
    const int sel = e >> 20;
    const int off = e & 0xFFFFF;
    const float* src = sel == 0 ? Wq : sel == 1 ? Wk : sel == 2 ? Wv : Wo;
    float4 v = *(const float4*)(src + off);
    if (sel < 3) {
        const float* gam = (sel == 0) ? gq : gkv;
        float4 g = *(const float4*)(gam + (off & 1023));  // i = fast dim of W[o][i]
        v.x *= g.x; v.y *= g.y; v.z *= g.z; v.w *= g.w;
        ushort4 h, l;
        h.x = f2bf(v.x); l.x = f2bf(v.x - bf2f(h.x));
        h.y = f2bf(v.y); l.y = f2bf(v.y - bf2f(h.y));
        h.z = f2bf(v.z); l.z = f2bf(v.z - bf2f(h.z));
        h.w = f2bf(v.w); l.w = f2bf(v.w - bf2f(h.w));
        unsigned short* hi = (unsigned short*)(ws + (size_t)sel * (4u << 20));
        unsigned short* lo = (unsigned short*)(ws + (size_t)sel * (4u << 20) + (2u << 20));
        *(ushort4*)(hi + off) = h;
        *(ushort4*)(lo + off) = l;
    } else {
        ushort4 o;
        o.x = f2bf(v.x); o.y = f2bf(v.y); o.z = f2bf(v.z); o.w = f2bf(v.w);
        *(ushort4*)((unsigned short*)(ws + (12u << 20)) + off) = o;
    }
}

// ---------------------------------------------------------------------------
// Row rsqrt scales: scale[row] = rsqrt(mean(x_row^2) + EPS_RMS)
// ---------------------------------------------------------------------------
__global__ __launch_bounds__(256)
void scales_kernel(const float* __restrict__ x, float* __restrict__ scale)
{
    const long row = blockIdx.x;
    float4 v = ((const float4*)(x + row * D_DIM))[threadIdx.x];
    float ss = v.x*v.x + v.y*v.y + v.z*v.z + v.w*v.w;
#pragma unroll
    for (int m = 32; m; m >>= 1) ss += __shfl_xor(ss, m);
    __shared__ float red[4];
    if ((threadIdx.x & 63) == 0) red[threadIdx.x >> 6] = ss;
    __syncthreads();
    if (threadIdx.x == 0) {
        float tot = red[0] + red[1] + red[2] + red[3];
        scale[row] = rsqrtf(tot * (1.0f / 1024.0f) + 1.1920929e-07f);
    }
}

// ---------------------------------------------------------------------------
// Split-bf16 GEMM: O[m,n] = rowscale[m] * sum_k A_f32[m,k] * (Bhi+Blo)[n,k]
// A f32 reg-staged + split to hi/lo in LDS; B hi/lo via global_load_lds.
// 3-MFMA per fragment pair (hh + lh + hl), f32 out. z selects (B,O) pair.
// ---------------------------------------------------------------------------
__global__ __launch_bounds__(256)
void gemm_split(const float* __restrict__ A,
                const unsigned short* __restrict__ Bh0, const unsigned short* __restrict__ Bl0,
                const unsigned short* __restrict__ Bh1, const unsigned short* __restrict__ Bl1,
                const float* __restrict__ rowscale,
                float* __restrict__ O0, float* __restrict__ O1)
{
    __shared__ unsigned short Ah[4096], Al[4096], Bh[4096], Bl[4096];
    const unsigned short* Bhp = blockIdx.z ? Bh1 : Bh0;
    const unsigned short* Blp = blockIdx.z ? Bl1 : Bl0;
    float* O = blockIdx.z ? O1 : O0;

    const int tid = threadIdx.x, lane = tid & 63, wave = tid >> 6;
    const int wm = wave >> 1, wn = wave & 1;
    const long Arow0 = (long)blockIdx.y * 128;
    const int  Brow0 = blockIdx.x * 128;

    f32x4 acc[4][4] = {};

    const int s0 = tid, s1 = tid + 256;
    const int b0row = s0 >> 2, b0k = (s0 & 3) * 8;
    const int b1row = s1 >> 2, b1k = (s1 & 3) * 8;
    const int fr = lane & 15, ks = lane >> 4;

    for (int kt = 0; kt < 32; ++kt) {
        const int k0 = kt * 32;
        // B tiles (hi, lo) -> LDS, async
        gload16(Bhp + (long)(Brow0 + b0row) * D_DIM + k0 + b0k, (char*)Bh + wave * 1024);
        gload16(Bhp + (long)(Brow0 + b1row) * D_DIM + k0 + b1k, (char*)Bh + 4096 + wave * 1024);
        gload16(Blp + (long)(Brow0 + b0row) * D_DIM + k0 + b0k, (char*)Bl + wave * 1024);
        gload16(Blp + (long)(Brow0 + b1row) * D_DIM + k0 + b1k, (char*)Bl + 4096 + wave * 1024);
        // A tile: f32 load, split hi/lo, ds_write
#pragma unroll
        for (int j = 0; j < 4; ++j) {
            const int f = tid + j * 256;
            const int row = f >> 3, kc = f & 7;
            float4 v = *(const float4*)(A + (Arow0 + row) * D_DIM + k0 + kc * 4);
            ushort4 h, l;
            h.x = f2bf(v.x); l.x = f2bf(v.x - bf2f(h.x));
            h.y = f2bf(v.y); l.y = f2bf(v.y - bf2f(h.y));
            h.z = f2bf(v.z); l.z = f2bf(v.z - bf2f(h.z));
            h.w = f2bf(v.w); l.w = f2bf(v.w - bf2f(h.w));
            *(ushort4*)((char*)Ah + f * 8) = h;
            *(ushort4*)((char*)Al + f * 8) = l;
        }
        __syncthreads();

        short8 ah[4], al[4], bh[4], bl[4];
        const unsigned short* Ahq = Ah + (wm * 64 + fr) * 32 + ks * 8;
        const unsigned short* Alq = Al + (wm * 64 + fr) * 32 + ks * 8;
        const unsigned short* Bhq = Bh + (wn * 64 + fr) * 32 + ks * 8;
        const unsigned short* Blq = Bl + (wn * 64 + fr) * 32 + ks * 8;
#pragma unroll
        for (int mi = 0; mi < 4; ++mi) {
            ah[mi] = *(const short8*)(Ahq + mi * 512);
            al[mi] = *(const short8*)(Alq + mi * 512);
        }
#pragma unroll
        for (int ni = 0; ni < 4; ++ni) {
            bh[ni] = *(const short8*)(Bhq + ni * 512);
            bl[ni] = *(const short8*)(Blq + ni * 512);
        }
#pragma unroll
        for (int mi = 0; mi < 4; ++mi)
#pragma unroll
            for (int ni = 0; ni < 4; ++ni) {
                acc[mi][ni] = __builtin_amdgcn_mfma_f32_16x16x32_bf16(ah[mi], bh[ni], acc[mi][ni], 0, 0, 0);
                acc[mi][ni] = __builtin_amdgcn_mfma_f32_16x16x32_bf16(al[mi], bh[ni], acc[mi][ni], 0, 0, 0);
                acc[mi][ni] = __builtin_amdgcn_mfma_f32_16x16x32_bf16(ah[mi], bl[ni], acc[mi][ni], 0, 0, 0);
            }
        __syncthreads();
    }

    const int c = lane & 15, r0 = (lane >> 4) * 4;
#pragma unroll
    for (int mi = 0; mi < 4; ++mi)
#pragma unroll
        for (int ni = 0; ni < 4; ++ni)
#pragma unroll
            for (int j = 0; j < 4; ++j) {
                const long row = Arow0 + wm * 64 + mi * 16 + r0 + j;
                const int  col = Brow0 + wn * 64 + ni * 16 + c;
                O[row * D_DIM + col] = acc[mi][ni][j] * rowscale[row];
            }
}

// ---------------------------------------------------------------------------
// Plain bf16 GEMM (m97 structure) for out = resid + ao @ Wo^T, f32 out.
// ---------------------------------------------------------------------------
__global__ __launch_bounds__(256)
void gemm_out(const unsigned short* __restrict__ A, const unsigned short* __restrict__ W,
              float* __restrict__ C, const float* __restrict__ resid)
{
    __shared__ unsigned short As[4096];
    __shared__ unsigned short Bs[4096];

    const int tid = threadIdx.x, lane = tid & 63, wave = tid >> 6;
    const int wm = wave >> 1, wn = wave & 1;
    const long Arow0 = (long)blockIdx.y * 128;
    const int  Brow0 = blockIdx.x * 128;

    f32x4 acc[4][4] = {};
    const int s0 = tid, s1 = tid + 256;
    const int a0row = s0 >> 2, a0k = (s0 & 3) * 8;
    const int a1row = s1 >> 2, a1k = (s1 & 3) * 8;
    const int fr = lane & 15, ks = lane >> 4;

    for (int kt = 0; kt < 32; ++kt) {
        const int k0 = kt * 32;
        gload16(A + (Arow0 + a0row) * D_DIM + k0 + a0k, (char*)As + wave * 1024);
        gload16(A + (Arow0 + a1row) * D_DIM + k0 + a1k, (char*)As + 4096 + wave * 1024);
        gload16(W + (long)(Brow0 + a0row) * D_DIM + k0 + a0k, (char*)Bs + wave * 1024);
        gload16(W + (long)(Brow0 + a1row) * D_DIM + k0 + a1k, (char*)Bs + 4096 + wave * 1024);
        __syncthreads();

        short8 a[4], b[4];
        const unsigned short* Ap = As + (wm * 64 + fr) * 32 + ks * 8;
        const unsigned short* Bp = Bs + (wn * 64 + fr) * 32 + ks * 8;
#pragma unroll
        for (int mi = 0; mi < 4; ++mi) a[mi] = *(const short8*)(Ap + mi * 512);
#pragma unroll
        for (int ni = 0; ni < 4; ++ni) b[ni] = *(const short8*)(Bp + ni * 512);
#pragma unroll
        for (int mi = 0; mi < 4; ++mi)
#pragma unroll
            for (int ni = 0; ni < 4; ++ni)
                acc[mi][ni] = __builtin_amdgcn_mfma_f32_16x16x32_bf16(a[mi], b[ni], acc[mi][ni], 0, 0, 0);
        __syncthreads();
    }

    const int c = lane & 15, r0 = (lane >> 4) * 4;
#pragma unroll
    for (int mi = 0; mi < 4; ++mi)
#pragma unroll
        for (int ni = 0; ni < 4; ++ni)
#pragma unroll
            for (int j = 0; j < 4; ++j) {
                const long row = Arow0 + wm * 64 + mi * 16 + r0 + j;
                const int  col = Brow0 + wn * 64 + ni * 16 + c;
                C[row * D_DIM + col] = resid[row * D_DIM + col] + acc[mi][ni][j];
            }
}

// ---------------------------------------------------------------------------
// Band attention (f32 q/k/v): |p-idx|<=1, s=qk/8, w=relu(s)^2, normalize, @v.
// One block per token; thread t: head h=t>>4, 4 dims at (t&15)*4.
// ---------------------------------------------------------------------------
__global__ __launch_bounds__(256)
void attn_kernel(const float* __restrict__ q, const float* __restrict__ kf,
                 const float* __restrict__ vf, const int* __restrict__ cidx,
                 unsigned short* __restrict__ ao, int token0)
{
    const int tlocal = blockIdx.x;
    const int token  = token0 + tlocal;
    const int b = token >> 12;
    const int h = threadIdx.x >> 4, g = threadIdx.x & 15;
    const int col = h * 64 + g * 4;
    const int idx = cidx[token];

    float4 qv = *(const float4*)(q + (long)tlocal * D_DIM + col);
    float a0 = 0.f, a1 = 0.f, a2 = 0.f, a3 = 0.f, wsum = 0.f;
#pragma unroll
    for (int dp = -1; dp <= 1; ++dp) {
        const int p = idx + dp;
        if (p < 0 || p >= 256) continue;
        const long roff = ((long)(b * 256 + p)) * D_DIM + col;
        float4 kv = *(const float4*)(kf + roff);
        float dot = qv.x*kv.x + qv.y*kv.y + qv.z*kv.z + qv.w*kv.w;
#pragma unroll
        for (int m = 1; m < 16; m <<= 1) dot += __shfl_xor(dot, m);
        const float s = dot * 0.125f;
        const float w = s > 0.f ? s * s : 0.f;
        wsum += w;
        float4 vv = *(const float4*)(vf + roff);
        a0 += w * vv.x; a1 += w * vv.y; a2 += w * vv.z; a3 += w * vv.w;
    }
    const float inv = 1.0f / fmaxf(wsum, 1e-6f);
    ushort4 o;
    o.x = f2bf(a0 * inv); o.y = f2bf(a1 * inv);
    o.z = f2bf(a2 * inv); o.w = f2bf(a3 * inv);
    *(ushort4*)(ao + (long)token * D_DIM + col) = o;
}

// ---------------------------------------------------------------------------
extern "C" void kernel_launch(void* const* d_in, const int* in_sizes, int n_in,
                              void* d_out, int out_size, void* d_ws, size_t ws_size,
                              hipStream_t stream)
{
    const float* x    = (const float*)d_in[0];
    const float* ctx  = (const float*)d_in[1];
    const int*   cidx = (const int*)d_in[2];
    const float* gq   = (const float*)d_in[3];
    const float* gkv  = (const float*)d_in[4];
    const float* Wq   = (const float*)d_in[5];
    const float* Wk   = (const float*)d_in[6];
    const float* Wv   = (const float*)d_in[7];
    const float* Wo   = (const float*)d_in[8];
    float* out = (float*)d_out;

    char* ws = (char*)d_ws;
    const size_t MB = 1 << 20;
    unsigned short* wq_hi = (unsigned short*)(ws + 0 * MB);
    unsigned short* wq_lo = (unsigned short*)(ws + 2 * MB);
    unsigned short* wk_hi = (unsigned short*)(ws + 4 * MB);
    unsigned short* wk_lo = (unsigned short*)(ws + 6 * MB);
    unsigned short* wv_hi = (unsigned short*)(ws + 8 * MB);
    unsigned short* wv_lo = (unsigned short*)(ws + 10 * MB);
    unsigned short* wo_b  = (unsigned short*)(ws + 12 * MB);
    float* scale_x = (float*)(ws + 14 * MB);            // 64KB
    float* scale_c = (float*)(ws + 14 * MB + 131072);   // 4KB
    float* k_f  = (float*)(ws + 15 * MB);               // 4MB
    float* v_f  = (float*)(ws + 19 * MB);               // 4MB
    float* q_f  = (float*)(ws + 23 * MB);               // 32MB (half: 8192x1024 f32)
    unsigned short* ao_b = (unsigned short*)(ws + 55 * MB);  // 32MB; total 87MB

    // 1. fold gamma into Wq/Wk/Wv, split hi/lo; Wo -> bf16
    convw_kernel<<<4096, 256, 0, stream>>>(Wq, Wk, Wv, Wo, gq, gkv, ws);
    // 2. rmsnorm row scales
    scales_kernel<<<16384, 256, 0, stream>>>(x, scale_x);
    scales_kernel<<<1024, 256, 0, stream>>>(ctx, scale_c);
    // 3. k,v = diag(scale_c) * ctx @ W'^T  (split precision, f32 out)
    gemm_split<<<dim3(8, 8, 2), 256, 0, stream>>>(ctx, wk_hi, wk_lo, wv_hi, wv_lo,
                                                  scale_c, k_f, v_f);
    // 4+5. q (split precision) + band attention, in two token halves
    for (int half = 0; half < 2; ++half) {
        const size_t ro = (size_t)half * 8192;
        gemm_split<<<dim3(8, 64, 1), 256, 0, stream>>>(x + ro * D_DIM,
                                                       wq_hi, wq_lo, wq_hi, wq_lo,
                                                       scale_x + ro, q_f, q_f);
        attn_kernel<<<8192, 256, 0, stream>>>(q_f, k_f, v_f, cidx, ao_b, (int)ro);
    }
    // 6. out = x + ao @ Wo^T
    gemm_out<<<dim3(8, 128, 1), 256, 0, stream>>>(ao_b, wo_b, out, x);
}